// Round 3
// baseline (463.025 us; speedup 1.0000x reference)
//
#include <hip/hip_runtime.h>
#include <hip/hip_bf16.h>
#include <math.h>

#define BB 8
#define HH 128
#define WW 128
#define CC 96
#define NPIX (BB*HH*WW)
#define WP 130                     // W padded by 1 on each side
#define XPLANE ((size_t)BB*HH*WP*32)   // elements per 32-channel plane
#define EPSF 1e-5f
#define FT_SMOOTH_F 1e-5f

typedef short short8 __attribute__((ext_vector_type(8)));
typedef float f32x4 __attribute__((ext_vector_type(4)));

#define GLDS(gp, lp) __builtin_amdgcn_global_load_lds( \
    (const __attribute__((address_space(1))) unsigned int*)(gp), \
    (__attribute__((address_space(3))) unsigned int*)(lp), 16, 0, 0)

__device__ __forceinline__ float ftanimoto(float tpl, float tpp, float tll) {
    float num = tpl + FT_SMOOTH_F;
    float denum = 0.0f;
    float a = 1.0f;
#pragma unroll
    for (int d = 0; d < 5; ++d) {
        float bco = -(2.0f * a - 1.0f);
        denum += 1.0f / (a * (tpp + tll) + bco * tpl + FT_SMOOTH_F);
        a *= 2.0f;
    }
    return num * denum * 0.2f;
}

__device__ __forceinline__ unsigned short f2bf(float f) {
    __hip_bfloat16 h = __float2bfloat16(f);
    return *(unsigned short*)&h;
}

__device__ __forceinline__ float bf2f(unsigned short u) {
    return __uint_as_float((unsigned int)u << 16);
}

// ---------------------------------------------------------------------------
// Cast + pad into [cc][b][h][wp][32] bf16 (zero W-border).
// Thread t -> (pixp, cc, ch8): reads 32 B fp32 coalesced, writes 16 B bf16.
// ---------------------------------------------------------------------------
__global__ __launch_bounds__(256) void cast_pad(const float* __restrict__ x,
                                                unsigned short* __restrict__ xp)
{
    const int tid = blockIdx.x * 256 + threadIdx.x;      // [pixp][cc][ch8]
    const int r12 = tid % 12;
    const int pixp = tid / 12;                           // (b*HH+h)*WP + wp
    const int cc = r12 >> 2;
    const int ch8 = r12 & 3;
    const int rowid = pixp / WP;                         // b*HH+h
    const int wp = pixp - rowid * WP;

    short8 o = (short8){0,0,0,0,0,0,0,0};
    if (wp > 0 && wp < WP - 1) {
        const float* src = x + (size_t)(rowid * WW + wp - 1) * CC + cc * 32 + ch8 * 8;
        const float4 v0 = *(const float4*)(src);
        const float4 v1 = *(const float4*)(src + 4);
        o[0] = (short)f2bf(v0.x); o[1] = (short)f2bf(v0.y);
        o[2] = (short)f2bf(v0.z); o[3] = (short)f2bf(v0.w);
        o[4] = (short)f2bf(v1.x); o[5] = (short)f2bf(v1.y);
        o[6] = (short)f2bf(v1.z); o[7] = (short)f2bf(v1.w);
    }
    *(short8*)(xp + (size_t)cc * XPLANE + (size_t)pixp * 32 + ch8 * 8) = o;
}

// ---------------------------------------------------------------------------
// Weight transpose+cast: w fp32 [864 k][96 co] -> wT bf16 [96 co][864 k].
// ---------------------------------------------------------------------------
__global__ __launch_bounds__(256) void cast_wT(const float* __restrict__ w,
                                               unsigned short* __restrict__ wT)
{
    const int tid = blockIdx.x * 256 + threadIdx.x;
    if (tid >= 864 * CC) return;
    const int co = tid % CC;
    const int k = tid / CC;
    wT[(size_t)co * 864 + k] = f2bf(w[tid]);
}

// ---------------------------------------------------------------------------
// Implicit-GEMM 3x3 conv, bf16 MFMA 16x16x32.
// cc-outer restructure: stage A-halo (4 rows x 130 px x 32 ci, 36.9 KB) once
// per cc chunk via global_load_lds(16B) with XOR chunk swizzle (2-way = free);
// then 9 taps x 24 MFMA/wave from LDS = 216 MFMA per barrier pair.
// B fragments read straight from global (weights L2-resident) into regs.
// ---------------------------------------------------------------------------
template<int FINAL>
__global__ __launch_bounds__(256, 3) void conv_gemm(
    const unsigned short* __restrict__ xpad, const unsigned short* __restrict__ wT,
    const float* __restrict__ g, const float* __restrict__ bt,
    const float* __restrict__ mu, const float* __restrict__ var,
    const float* __restrict__ attc, const float* __restrict__ atts,
    const float* __restrict__ gnp, const float* __restrict__ bnbp,
    const float* __restrict__ mnp, const float* __restrict__ vnp,
    unsigned short* __restrict__ qout, float* __restrict__ fout)
{
    __shared__ __align__(16) char smem[4 * 9216];   // 4 rows x 144 px x 64 B
    const int tid = threadIdx.x;
    const int wv = tid >> 6;
    const int L  = tid & 63;
    const int blk = blockIdx.x;
    const int b  = blk >> 6;
    const int h0 = (blk & 63) << 1;
    const int hrow = h0 + (wv >> 1);
    const int wwbase = (wv & 1) << 6;
    const int lrow = L & 15;
    const int qq = L >> 4;

    // staging: wave wv stages LDS row wv <- input row h0-1+wv
    const int hst = h0 - 1 + wv;
    const bool stv = (hst >= 0) && (hst < HH);
    const int sp = L >> 2;          // pixel offset within 16-px group
    const int c_slot = L & 3;

    f32x4 acc[4][6];
#pragma unroll
    for (int mt = 0; mt < 4; ++mt)
#pragma unroll
        for (int nt = 0; nt < 6; ++nt) acc[mt][nt] = (f32x4){0.f, 0.f, 0.f, 0.f};

    for (int cc = 0; cc < 3; ++cc) {
        __syncthreads();                            // LDS safe to overwrite
        if (stv) {
            const size_t rowg = (size_t)cc * XPLANE + (size_t)((b * HH + hst) * WP) * 32;
            char* ldsrow = smem + wv * 9216;
#pragma unroll
            for (int j = 0; j < 9; ++j) {
                const int p = j * 16 + sp;
                const int csrc = c_slot ^ ((p ^ (p >> 2)) & 3);
                GLDS(xpad + rowg + (size_t)p * 32 + csrc * 8, ldsrow + j * 1024);
            }
        }
        __syncthreads();                            // staging visible
#pragma unroll
        for (int dy = -1; dy <= 1; ++dy) {
            const int hh = hrow + dy;
            if (hh < 0 || hh >= HH) continue;       // wave-uniform
            const char* ldsrow = smem + (dy + 1 + (wv >> 1)) * 9216;
#pragma unroll
            for (int dx = -1; dx <= 1; ++dx) {
                const int tap = (dy + 1) * 3 + (dx + 1);
                short8 bf[6];
#pragma unroll
                for (int nt = 0; nt < 6; ++nt)
                    bf[nt] = *(const short8*)(wT + (size_t)(nt * 16 + lrow) * 864
                                              + tap * 96 + cc * 32 + qq * 8);
                short8 af[4];
#pragma unroll
                for (int mt = 0; mt < 4; ++mt) {
                    const int p = wwbase + mt * 16 + lrow + dx + 1;
                    const int slot = qq ^ ((p ^ (p >> 2)) & 3);
                    af[mt] = *(const short8*)(ldsrow + p * 64 + slot * 16);
                }
#pragma unroll
                for (int nt = 0; nt < 6; ++nt)
#pragma unroll
                    for (int mt = 0; mt < 4; ++mt)
                        acc[mt][nt] = __builtin_amdgcn_mfma_f32_16x16x32_bf16(
                            af[mt], bf[nt], acc[mt][nt], 0, 0, 0);
            }
        }
    }

    // epilogue: C layout col=lane&15, row=(lane>>4)*4+reg
#pragma unroll
    for (int nt = 0; nt < 6; ++nt) {
        const int co = nt * 16 + lrow;
        const float scl = g[co] * rsqrtf(var[co] + EPSF);
        const float sft = bt[co] - mu[co] * scl;
        float nscl = 0.f, nsft = 0.f, ac = 0.f;
        if (FINAL) {
            nscl = gnp[co] * rsqrtf(vnp[co] + EPSF);
            nsft = bnbp[co] - mnp[co] * nscl;
            ac = attc[b * CC + co];
        }
#pragma unroll
        for (int mt = 0; mt < 4; ++mt) {
#pragma unroll
            for (int r = 0; r < 4; ++r) {
                const int row = (wv << 6) + (mt << 4) + (qq << 2) + r;
                const int h = h0 + (row >> 7);
                const int w = row & 127;
                const size_t pix = (size_t)(b * HH + h) * WW + w;
                const float t = acc[mt][nt][r] * scl + sft;
                const float sig = 1.0f / (1.0f + expf(-t));
                if (!FINAL) {
                    qout[pix * CC + co] = f2bf(sig);
                } else {
                    const float att = 0.5f * (ac + atts[pix]);
                    fout[pix * CC + co] = att * sig * nscl + nsft;
                }
            }
        }
    }
}

// ---------------------------------------------------------------------------
// Spatial attention: one wave per pixel, reduce over C=96 (uint = 2 bf16/lane).
// ---------------------------------------------------------------------------
__global__ __launch_bounds__(256) void spatial_att(
    const unsigned short* __restrict__ qb, const unsigned short* __restrict__ kb,
    float* __restrict__ atts)
{
    const int gid = blockIdx.x * 256 + threadIdx.x;
    const int pix = gid >> 6;
    const int lane = threadIdx.x & 63;
    float tpl = 0.f, tpp = 0.f, tll = 0.f;
    if (lane < 48) {
        const unsigned int qu = ((const unsigned int*)qb)[(size_t)pix * 48 + lane];
        const unsigned int ku = ((const unsigned int*)kb)[(size_t)pix * 48 + lane];
        const float q0 = __uint_as_float(qu << 16);
        const float q1 = __uint_as_float(qu & 0xffff0000u);
        const float k0 = __uint_as_float(ku << 16);
        const float k1 = __uint_as_float(ku & 0xffff0000u);
        tpl = q0 * k0 + q1 * k1;
        tpp = q0 * q0 + q1 * q1;
        tll = k0 * k0 + k1 * k1;
    }
#pragma unroll
    for (int off = 32; off > 0; off >>= 1) {
        tpl += __shfl_xor(tpl, off);
        tpp += __shfl_xor(tpp, off);
        tll += __shfl_xor(tll, off);
    }
    if (lane == 0) atts[pix] = ftanimoto(tpl, tpp, tll);
}

// ---------------------------------------------------------------------------
// Channel attention stage 1: block=192 (16 pixel-groups x 12 chan-chunks),
// 16-B vector loads; LDS reduce across groups; per (b, 256-px slab, c) out.
// ---------------------------------------------------------------------------
__global__ __launch_bounds__(192) void chan_partial(
    const unsigned short* __restrict__ qb, const unsigned short* __restrict__ kb,
    float* __restrict__ part)
{
    __shared__ float red[16][12][24];
    const int t = threadIdx.x;
    const int g = t / 12;
    const int c8 = t - g * 12;
    const int b = blockIdx.x >> 6;
    const int slab = blockIdx.x & 63;
    const size_t p0 = (size_t)b * HH * WW + (size_t)slab * 256;

    float s_tpl[8], s_tpp[8], s_tll[8];
#pragma unroll
    for (int j = 0; j < 8; ++j) { s_tpl[j] = 0.f; s_tpp[j] = 0.f; s_tll[j] = 0.f; }

    for (int i = 0; i < 16; ++i) {
        const size_t pe = (p0 + g + i * 16) * CC + c8 * 8;
        const short8 qv = *(const short8*)(qb + pe);
        const short8 kv = *(const short8*)(kb + pe);
#pragma unroll
        for (int j = 0; j < 8; ++j) {
            const float qf = bf2f((unsigned short)qv[j]);
            const float kf = bf2f((unsigned short)kv[j]);
            s_tpl[j] = fmaf(qf, kf, s_tpl[j]);
            s_tpp[j] = fmaf(qf, qf, s_tpp[j]);
            s_tll[j] = fmaf(kf, kf, s_tll[j]);
        }
    }
#pragma unroll
    for (int j = 0; j < 8; ++j) {
        red[g][c8][0 * 8 + j] = s_tpl[j];
        red[g][c8][1 * 8 + j] = s_tpp[j];
        red[g][c8][2 * 8 + j] = s_tll[j];
    }
    __syncthreads();
    if (t < CC) {
        const int cg = t >> 3, cj = t & 7;
        float tpl = 0.f, tpp = 0.f, tll = 0.f;
        for (int gg = 0; gg < 16; ++gg) {
            tpl += red[gg][cg][0 * 8 + cj];
            tpp += red[gg][cg][1 * 8 + cj];
            tll += red[gg][cg][2 * 8 + cj];
        }
        const size_t idx = ((size_t)blockIdx.x * CC + t) * 3;
        part[idx + 0] = tpl;
        part[idx + 1] = tpp;
        part[idx + 2] = tll;
    }
}

// ---------------------------------------------------------------------------
// Channel attention stage 2: one block per b, reduce 64 slab partials.
// ---------------------------------------------------------------------------
__global__ __launch_bounds__(128) void chan_final(
    const float* __restrict__ part, float* __restrict__ attc)
{
    const int b = blockIdx.x;
    const int c = threadIdx.x;
    if (c >= CC) return;
    float tpl = 0.f, tpp = 0.f, tll = 0.f;
    for (int s = 0; s < 64; ++s) {
        const size_t idx = (((size_t)(b * 64 + s)) * CC + c) * 3;
        tpl += part[idx + 0];
        tpp += part[idx + 1];
        tll += part[idx + 2];
    }
    attc[b * CC + c] = ftanimoto(tpl, tpp, tll);
}

extern "C" void kernel_launch(void* const* d_in, const int* in_sizes, int n_in,
                              void* d_out, int out_size, void* d_ws, size_t ws_size,
                              hipStream_t stream)
{
    const float* x1 = (const float*)d_in[0];
    const float* x2 = (const float*)d_in[1];
    const float* x3 = (const float*)d_in[2];
    const float* wq = (const float*)d_in[3];
    const float* gq = (const float*)d_in[4];
    const float* bq = (const float*)d_in[5];
    const float* mq = (const float*)d_in[6];
    const float* vq = (const float*)d_in[7];
    const float* wk = (const float*)d_in[8];
    const float* gk = (const float*)d_in[9];
    const float* bk = (const float*)d_in[10];
    const float* mk = (const float*)d_in[11];
    const float* vk = (const float*)d_in[12];
    const float* wvw = (const float*)d_in[13];
    const float* gv = (const float*)d_in[14];
    const float* bv = (const float*)d_in[15];
    const float* mv = (const float*)d_in[16];
    const float* vv = (const float*)d_in[17];
    const float* gn = (const float*)d_in[18];
    const float* bnb = (const float*)d_in[19];
    const float* mn = (const float*)d_in[20];
    const float* vn = (const float*)d_in[21];

    // workspace layout (~27 MB)
    unsigned short* xpad = (unsigned short*)d_ws;               // 3*XPLANE + slack
    const size_t xpadElems = 3 * XPLANE + 512;
    char* wsp = (char*)d_ws + xpadElems * 2;
    unsigned short* wT = (unsigned short*)wsp;                  // 96*864 bf16
    float* atts = (float*)(wsp + 864 * CC * 2);                 // NPIX fp32
    float* part = atts + NPIX;                                  // 512*96*3
    float* attc = part + (size_t)512 * CC * 3;                  // 768

    // q,k bf16 live inside d_out (dead before final conv writes fp32)
    unsigned short* qb = (unsigned short*)d_out;
    unsigned short* kb = qb + (size_t)NPIX * CC;

    const int padBlocks = (BB * HH * WP * 12) / 256;   // 6240, exact
    const int wtBlocks = (864 * CC + 255) / 256;       // 324

    cast_wT<<<wtBlocks, 256, 0, stream>>>(wq, wT);
    cast_pad<<<padBlocks, 256, 0, stream>>>(x1, xpad);
    conv_gemm<0><<<512, 256, 0, stream>>>(xpad, wT, gq, bq, mq, vq,
                                          nullptr, nullptr, nullptr, nullptr, nullptr, nullptr,
                                          qb, nullptr);
    cast_wT<<<wtBlocks, 256, 0, stream>>>(wk, wT);
    cast_pad<<<padBlocks, 256, 0, stream>>>(x2, xpad);
    conv_gemm<0><<<512, 256, 0, stream>>>(xpad, wT, gk, bk, mk, vk,
                                          nullptr, nullptr, nullptr, nullptr, nullptr, nullptr,
                                          kb, nullptr);
    spatial_att<<<NPIX / 4, 256, 0, stream>>>(qb, kb, atts);
    chan_partial<<<BB * 64, 192, 0, stream>>>(qb, kb, part);
    chan_final<<<BB, 128, 0, stream>>>(part, attc);
    cast_wT<<<wtBlocks, 256, 0, stream>>>(wvw, wT);
    cast_pad<<<padBlocks, 256, 0, stream>>>(x3, xpad);
    conv_gemm<1><<<512, 256, 0, stream>>>(xpad, wT, gv, bv, mv, vv,
                                          attc, atts, gn, bnb, mn, vn,
                                          nullptr, (float*)d_out);
}

// Round 4
// 366.388 us; speedup vs baseline: 1.2638x; 1.2638x over previous
//
#include <hip/hip_runtime.h>
#include <hip/hip_bf16.h>
#include <math.h>

#define BB 8
#define HH 128
#define WW 128
#define CC 96
#define NPIX (BB*HH*WW)
#define EPSF 1e-5f
#define FT_SMOOTH_F 1e-5f
#define ROWB 8320                 // 130 px x 64 B per LDS row
#define WELEM 82944               // 864*96 weight elements per conv

typedef short short8 __attribute__((ext_vector_type(8)));
typedef float f32x4 __attribute__((ext_vector_type(4)));

__device__ __forceinline__ float ftanimoto(float tpl, float tpp, float tll) {
    float num = tpl + FT_SMOOTH_F;
    float denum = 0.0f;
    float a = 1.0f;
#pragma unroll
    for (int d = 0; d < 5; ++d) {
        float bco = -(2.0f * a - 1.0f);
        denum += 1.0f / (a * (tpp + tll) + bco * tpl + FT_SMOOTH_F);
        a *= 2.0f;
    }
    return num * denum * 0.2f;
}

__device__ __forceinline__ unsigned short f2bf(float f) {
    __hip_bfloat16 h = __float2bfloat16(f);
    return *(unsigned short*)&h;
}

__device__ __forceinline__ float bf2f(unsigned short u) {
    return __uint_as_float((unsigned int)u << 16);
}

// ---------------------------------------------------------------------------
// Weight repack (all 3 convs, one dispatch): w fp32 [tap][ci][co] ->
// wT2 bf16 [cid][tap][cc][nt][lrow*4+qq][8j] so a B-fragment load is one
// contiguous 1 KB wave read.
// ---------------------------------------------------------------------------
__global__ __launch_bounds__(256) void cast_wT2(
    const float* __restrict__ wq, const float* __restrict__ wk,
    const float* __restrict__ wv, unsigned short* __restrict__ wT2)
{
    const int tid = blockIdx.x * 256 + threadIdx.x;
    if (tid >= 3 * WELEM) return;
    const int cid = tid / WELEM;
    const int o = tid - cid * WELEM;
    const int j = o & 7;
    const int rest = o >> 3;
    const int lq = rest & 63;
    const int lrow = lq >> 2, qq = lq & 3;
    const int tile = rest >> 6;          // (tap*3+cc)*6+nt
    const int nt = tile % 6;
    const int tcc = tile / 6;
    const int cc = tcc % 3, tap = tcc / 3;
    const int ci = cc * 32 + qq * 8 + j;
    const int co = nt * 16 + lrow;
    const float* w = (cid == 0) ? wq : (cid == 1) ? wk : wv;
    wT2[tid] = f2bf(w[(size_t)(tap * CC + ci) * CC + co]);
}

// ---------------------------------------------------------------------------
// Fused cast + implicit-GEMM 3x3 conv for q, k, v in ONE dispatch.
// 1536 blocks: cid = blk/512 selects input/weights/BN/output.
// Block: 4 waves, 256 pixels (two W-rows) x 96 cout.
// Per cc chunk: each wave stages its input row (fp32 -> bf16 -> LDS with XOR
// chunk swizzle), then 9 taps x 24 MFMA/wave = 216 MFMA per barrier pair.
// B from coalesced wT2 (1 KB contiguous wave loads, L1-resident).
// Output: sigmoid(bn(conv)) as bf16.
// ---------------------------------------------------------------------------
__global__ __launch_bounds__(256, 3) void conv_all(
    const float* __restrict__ x1, const float* __restrict__ x2,
    const float* __restrict__ x3, const unsigned short* __restrict__ wT2,
    const float* __restrict__ gq, const float* __restrict__ bq,
    const float* __restrict__ mq, const float* __restrict__ vq,
    const float* __restrict__ gk, const float* __restrict__ bk,
    const float* __restrict__ mk, const float* __restrict__ vk,
    const float* __restrict__ gv, const float* __restrict__ bv,
    const float* __restrict__ mv, const float* __restrict__ vv,
    unsigned short* __restrict__ qb, unsigned short* __restrict__ kb,
    unsigned short* __restrict__ vb)
{
    __shared__ __align__(16) char smem[4 * ROWB];     // 33,280 B
    const int tid = threadIdx.x;
    const int wv = tid >> 6;
    const int L  = tid & 63;
    const int cid = blockIdx.x >> 9;                  // 0:q 1:k 2:v
    const int blk = blockIdx.x & 511;
    const int b  = blk >> 6;
    const int h0 = (blk & 63) << 1;
    const int hrow = h0 + (wv >> 1);
    const int wwbase = (wv & 1) << 6;
    const int lrow = L & 15;
    const int qq = L >> 4;

    const float* xsrc = (cid == 0) ? x1 : (cid == 1) ? x2 : x3;
    const unsigned short* wT2p = wT2 + (size_t)cid * WELEM;

    // staging: wave wv stages LDS row wv <- input image row h0-1+wv
    const int hst = h0 - 1 + wv;
    const bool stv = (hst >= 0) && (hst < HH);
    const float* xrow = xsrc + (size_t)(b * HH + (stv ? hst : 0)) * WW * CC;
    char* myrow = smem + wv * ROWB;

    f32x4 acc[4][6];
#pragma unroll
    for (int mt = 0; mt < 4; ++mt)
#pragma unroll
        for (int nt = 0; nt < 6; ++nt) acc[mt][nt] = (f32x4){0.f, 0.f, 0.f, 0.f};

    for (int cc = 0; cc < 3; ++cc) {
        __syncthreads();                              // LDS safe to overwrite
        if (stv) {
#pragma unroll
            for (int it = 0; it < 9; ++it) {
                const int idx = it * 64 + L;          // chunk job: 130 px x 4 chunks
                if (idx < 520) {
                    const int p = idx >> 2;           // lds pixel slot 0..129
                    const int c = idx & 3;            // 8-elem chunk
                    const int w = p - 1;              // image w = -1..128
                    short8 o = (short8){0,0,0,0,0,0,0,0};
                    if (w >= 0 && w < WW) {
                        const float* src = xrow + (size_t)w * CC + cc * 32 + c * 8;
                        const float4 a0 = *(const float4*)src;
                        const float4 a1 = *(const float4*)(src + 4);
                        o[0] = (short)f2bf(a0.x); o[1] = (short)f2bf(a0.y);
                        o[2] = (short)f2bf(a0.z); o[3] = (short)f2bf(a0.w);
                        o[4] = (short)f2bf(a1.x); o[5] = (short)f2bf(a1.y);
                        o[6] = (short)f2bf(a1.z); o[7] = (short)f2bf(a1.w);
                    }
                    const int slot = c ^ ((p ^ (p >> 2)) & 3);
                    *(short8*)(myrow + p * 64 + slot * 16) = o;
                }
            }
        }
        __syncthreads();                              // staging visible
#pragma unroll
        for (int dy = -1; dy <= 1; ++dy) {
            const int hh = hrow + dy;
            if (hh < 0 || hh >= HH) continue;         // wave-uniform skip
            const char* ldsrow = smem + (dy + 1 + (wv >> 1)) * ROWB;
#pragma unroll
            for (int dx = -1; dx <= 1; ++dx) {
                const int tap = (dy + 1) * 3 + (dx + 1);
                const unsigned short* bsrc = wT2p + (size_t)(tap * 3 + cc) * 6 * 512;
                short8 bf[6];
#pragma unroll
                for (int nt = 0; nt < 6; ++nt)
                    bf[nt] = *(const short8*)(bsrc + nt * 512 + (lrow * 4 + qq) * 8);
                short8 af[4];
#pragma unroll
                for (int mt = 0; mt < 4; ++mt) {
                    const int p = wwbase + mt * 16 + lrow + dx + 1;
                    const int slot = qq ^ ((p ^ (p >> 2)) & 3);
                    af[mt] = *(const short8*)(ldsrow + p * 64 + slot * 16);
                }
#pragma unroll
                for (int nt = 0; nt < 6; ++nt)
#pragma unroll
                    for (int mt = 0; mt < 4; ++mt)
                        acc[mt][nt] = __builtin_amdgcn_mfma_f32_16x16x32_bf16(
                            af[mt], bf[nt], acc[mt][nt], 0, 0, 0);
            }
        }
    }

    const float* g  = (cid == 0) ? gq : (cid == 1) ? gk : gv;
    const float* bt = (cid == 0) ? bq : (cid == 1) ? bk : bv;
    const float* mu = (cid == 0) ? mq : (cid == 1) ? mk : mv;
    const float* var = (cid == 0) ? vq : (cid == 1) ? vk : vv;
    unsigned short* outp = (cid == 0) ? qb : (cid == 1) ? kb : vb;

    // epilogue: C layout col=lane&15, row=(lane>>4)*4+reg
#pragma unroll
    for (int nt = 0; nt < 6; ++nt) {
        const int co = nt * 16 + lrow;
        const float scl = g[co] * rsqrtf(var[co] + EPSF);
        const float sft = bt[co] - mu[co] * scl;
#pragma unroll
        for (int mt = 0; mt < 4; ++mt) {
#pragma unroll
            for (int r = 0; r < 4; ++r) {
                const int row = (wv << 6) + (mt << 4) + (qq << 2) + r;
                const int h = h0 + (row >> 7);
                const int w = row & 127;
                const size_t pix = (size_t)(b * HH + h) * WW + w;
                const float t = acc[mt][nt][r] * scl + sft;
                outp[pix * CC + co] = f2bf(1.0f / (1.0f + expf(-t)));
            }
        }
    }
}

// ---------------------------------------------------------------------------
// Spatial attention: one wave per pixel, reduce over C=96 (uint = 2 bf16/lane).
// ---------------------------------------------------------------------------
__global__ __launch_bounds__(256) void spatial_att(
    const unsigned short* __restrict__ qb, const unsigned short* __restrict__ kb,
    float* __restrict__ atts)
{
    const int gid = blockIdx.x * 256 + threadIdx.x;
    const int pix = gid >> 6;
    const int lane = threadIdx.x & 63;
    float tpl = 0.f, tpp = 0.f, tll = 0.f;
    if (lane < 48) {
        const unsigned int qu = ((const unsigned int*)qb)[(size_t)pix * 48 + lane];
        const unsigned int ku = ((const unsigned int*)kb)[(size_t)pix * 48 + lane];
        const float q0 = __uint_as_float(qu << 16);
        const float q1 = __uint_as_float(qu & 0xffff0000u);
        const float k0 = __uint_as_float(ku << 16);
        const float k1 = __uint_as_float(ku & 0xffff0000u);
        tpl = q0 * k0 + q1 * k1;
        tpp = q0 * q0 + q1 * q1;
        tll = k0 * k0 + k1 * k1;
    }
#pragma unroll
    for (int off = 32; off > 0; off >>= 1) {
        tpl += __shfl_xor(tpl, off);
        tpp += __shfl_xor(tpp, off);
        tll += __shfl_xor(tll, off);
    }
    if (lane == 0) atts[pix] = ftanimoto(tpl, tpp, tll);
}

// ---------------------------------------------------------------------------
// Channel attention stage 1: block=192 (16 pixel-groups x 12 chan-chunks),
// 16-B vector loads; LDS reduce across groups; per (b, 256-px slab, c) out.
// ---------------------------------------------------------------------------
__global__ __launch_bounds__(192) void chan_partial(
    const unsigned short* __restrict__ qb, const unsigned short* __restrict__ kb,
    float* __restrict__ part)
{
    __shared__ float red[16][12][24];
    const int t = threadIdx.x;
    const int g = t / 12;
    const int c8 = t - g * 12;
    const int b = blockIdx.x >> 6;
    const int slab = blockIdx.x & 63;
    const size_t p0 = (size_t)b * HH * WW + (size_t)slab * 256;

    float s_tpl[8], s_tpp[8], s_tll[8];
#pragma unroll
    for (int j = 0; j < 8; ++j) { s_tpl[j] = 0.f; s_tpp[j] = 0.f; s_tll[j] = 0.f; }

    for (int i = 0; i < 16; ++i) {
        const size_t pe = (p0 + g + i * 16) * CC + c8 * 8;
        const short8 qv = *(const short8*)(qb + pe);
        const short8 kv = *(const short8*)(kb + pe);
#pragma unroll
        for (int j = 0; j < 8; ++j) {
            const float qf = bf2f((unsigned short)qv[j]);
            const float kf = bf2f((unsigned short)kv[j]);
            s_tpl[j] = fmaf(qf, kf, s_tpl[j]);
            s_tpp[j] = fmaf(qf, qf, s_tpp[j]);
            s_tll[j] = fmaf(kf, kf, s_tll[j]);
        }
    }
#pragma unroll
    for (int j = 0; j < 8; ++j) {
        red[g][c8][0 * 8 + j] = s_tpl[j];
        red[g][c8][1 * 8 + j] = s_tpp[j];
        red[g][c8][2 * 8 + j] = s_tll[j];
    }
    __syncthreads();
    if (t < CC) {
        const int cg = t >> 3, cj = t & 7;
        float tpl = 0.f, tpp = 0.f, tll = 0.f;
        for (int gg = 0; gg < 16; ++gg) {
            tpl += red[gg][cg][0 * 8 + cj];
            tpp += red[gg][cg][1 * 8 + cj];
            tll += red[gg][cg][2 * 8 + cj];
        }
        const size_t idx = ((size_t)blockIdx.x * CC + t) * 3;
        part[idx + 0] = tpl;
        part[idx + 1] = tpp;
        part[idx + 2] = tll;
    }
}

// ---------------------------------------------------------------------------
// Channel attention stage 2: one block per b, reduce 64 slab partials.
// ---------------------------------------------------------------------------
__global__ __launch_bounds__(128) void chan_final(
    const float* __restrict__ part, float* __restrict__ attc)
{
    const int b = blockIdx.x;
    const int c = threadIdx.x;
    if (c >= CC) return;
    float tpl = 0.f, tpp = 0.f, tll = 0.f;
    for (int s = 0; s < 64; ++s) {
        const size_t idx = (((size_t)(b * 64 + s)) * CC + c) * 3;
        tpl += part[idx + 0];
        tpp += part[idx + 1];
        tll += part[idx + 2];
    }
    attc[b * CC + c] = ftanimoto(tpl, tpp, tll);
}

// ---------------------------------------------------------------------------
// Final combine: out = bn(0.5*(attc+atts)*v). Reads v bf16, writes fp32.
// ---------------------------------------------------------------------------
__global__ __launch_bounds__(256) void final_combine(
    const unsigned short* __restrict__ vb, const float* __restrict__ atts,
    const float* __restrict__ attc,
    const float* __restrict__ gn, const float* __restrict__ bnb,
    const float* __restrict__ mn, const float* __restrict__ vn,
    float* __restrict__ out)
{
    const int tid = blockIdx.x * 256 + threadIdx.x;   // NPIX*12 jobs
    const int c8 = tid % 12;
    const int pix = tid / 12;
    const int b = pix >> 14;                          // HH*WW = 16384
    const short8 v = *(const short8*)(vb + (size_t)pix * CC + c8 * 8);
    const float as = atts[pix];
    float r[8];
#pragma unroll
    for (int j = 0; j < 8; ++j) {
        const int co = c8 * 8 + j;
        const float nscl = gn[co] * rsqrtf(vn[co] + EPSF);
        const float nsft = bnb[co] - mn[co] * nscl;
        const float att = 0.5f * (attc[b * CC + co] + as);
        r[j] = att * bf2f((unsigned short)v[j]) * nscl + nsft;
    }
    float* dst = out + (size_t)pix * CC + c8 * 8;
    *(float4*)dst = make_float4(r[0], r[1], r[2], r[3]);
    *(float4*)(dst + 4) = make_float4(r[4], r[5], r[6], r[7]);
}

extern "C" void kernel_launch(void* const* d_in, const int* in_sizes, int n_in,
                              void* d_out, int out_size, void* d_ws, size_t ws_size,
                              hipStream_t stream)
{
    const float* x1 = (const float*)d_in[0];
    const float* x2 = (const float*)d_in[1];
    const float* x3 = (const float*)d_in[2];
    const float* wq = (const float*)d_in[3];
    const float* gq = (const float*)d_in[4];
    const float* bq = (const float*)d_in[5];
    const float* mq = (const float*)d_in[6];
    const float* vq = (const float*)d_in[7];
    const float* wk = (const float*)d_in[8];
    const float* gk = (const float*)d_in[9];
    const float* bk = (const float*)d_in[10];
    const float* mk = (const float*)d_in[11];
    const float* vk = (const float*)d_in[12];
    const float* wvw = (const float*)d_in[13];
    const float* gv = (const float*)d_in[14];
    const float* bv = (const float*)d_in[15];
    const float* mv = (const float*)d_in[16];
    const float* vv = (const float*)d_in[17];
    const float* gn = (const float*)d_in[18];
    const float* bnb = (const float*)d_in[19];
    const float* mn = (const float*)d_in[20];
    const float* vn = (const float*)d_in[21];

    // workspace (~27 MB): wT2 | vb | atts | part | attc
    unsigned short* wT2 = (unsigned short*)d_ws;                  // 3*82944 bf16
    unsigned short* vb = wT2 + (size_t)3 * WELEM;                 // NPIX*96 bf16
    float* atts = (float*)(vb + (size_t)NPIX * CC);               // NPIX fp32
    float* part = atts + NPIX;                                    // 512*96*3
    float* attc = part + (size_t)512 * CC * 3;                    // 768

    // q,k bf16 exactly fill d_out; dead before final_combine writes fp32
    unsigned short* qb = (unsigned short*)d_out;
    unsigned short* kb = qb + (size_t)NPIX * CC;

    cast_wT2<<<(3 * WELEM + 255) / 256, 256, 0, stream>>>(wq, wk, wvw, wT2);
    conv_all<<<1536, 256, 0, stream>>>(x1, x2, x3, wT2,
                                       gq, bq, mq, vq, gk, bk, mk, vk,
                                       gv, bv, mv, vv, qb, kb, vb);
    spatial_att<<<NPIX / 4, 256, 0, stream>>>(qb, kb, atts);
    chan_partial<<<BB * 64, 192, 0, stream>>>(qb, kb, part);
    chan_final<<<BB, 128, 0, stream>>>(part, attc);
    final_combine<<<NPIX * 12 / 256, 256, 0, stream>>>(vb, atts, attc,
                                                       gn, bnb, mn, vn,
                                                       (float*)d_out);
}